// Round 18
// baseline (592.333 us; speedup 1.0000x reference)
//
#include <hip/hip_runtime.h>
#include <hip/hip_bf16.h>
#include <hip/hip_cooperative_groups.h>

namespace cg = cooperative_groups;

#define N_NODES 100000
#define N_EDGES 1600000
#define NBUCK 256
#define NODES_PER_BUCKET 391        // 256*391 = 100096 >= 100000
#define EDGES_PER_CHUNK (N_EDGES / NBUCK)   // 6250 exactly
#define FILL_LDS_CAP 8192           // mean 6250, sigma~79 -> +24 sigma

typedef __bf16 bf16x8 __attribute__((ext_vector_type(8)));
typedef float f32x4 __attribute__((ext_vector_type(4)));

// ---------------- helpers ----------------

__device__ inline unsigned short f2bf_rne(float v) {
    unsigned u = __float_as_uint(v);
    u += 0x7fffu + ((u >> 16) & 1u);
    return (unsigned short)(u >> 16);
}

__device__ inline unsigned pack_bf(float a, float b) {
    return (unsigned)f2bf_rne(a) | ((unsigned)f2bf_rne(b) << 16);
}

__device__ inline void acc8_bf(float* a, uint4 p) {
    a[0] += __uint_as_float(p.x << 16);
    a[1] += __uint_as_float(p.x & 0xffff0000u);
    a[2] += __uint_as_float(p.y << 16);
    a[3] += __uint_as_float(p.y & 0xffff0000u);
    a[4] += __uint_as_float(p.z << 16);
    a[5] += __uint_as_float(p.z & 0xffff0000u);
    a[6] += __uint_as_float(p.w << 16);
    a[7] += __uint_as_float(p.w & 0xffff0000u);
}

// ---------------- CSR build: single cooperative kernel --------------------
// Phases: A count (edges -> LDS once), B per-bucket scan, C bucket-total
// scan, D LDS-sort + coalesced staging write, E per-bucket fill.
// 256 blocks x 512 thr, ~104 KB LDS -> 1 block/CU, co-resident on 256 CUs.

__global__ __launch_bounds__(512) void csr_coop(const int* __restrict__ src,
                                                const int* __restrict__ dst,
                                                int* __restrict__ blkCntT,
                                                int* __restrict__ blkBaseL,
                                                int* __restrict__ bucketTotal,
                                                int* __restrict__ bstart,
                                                int2* __restrict__ staging,
                                                int* __restrict__ ssrc,
                                                int* __restrict__ offsets,
                                                float* __restrict__ inv_deg) {
    __shared__ __align__(16) char smem[106496];
    int2* bufRaw   = (int2*)smem;              // 50000 B
    int2* bufSrt   = (int2*)(smem + 50000);    // 50000 B
    int*  hist     = (int*)(smem + 100000);
    int*  runStart = (int*)(smem + 101024);
    int*  cur      = (int*)(smem + 102048);
    int*  gbase    = (int*)(smem + 103072);
    int*  sscan    = (int*)(smem + 104096);    // 256 ints

    cg::grid_group grid = cg::this_grid();
    const int tid = threadIdx.x;
    const int g = blockIdx.x;
    const int b0 = g * EDGES_PER_CHUNK;
    const int b1 = min(b0 + EDGES_PER_CHUNK, N_EDGES);
    const int cnt = b1 - b0;

    // --- phase A: load edges to LDS + histogram ---
    if (tid < NBUCK) hist[tid] = 0;
    __syncthreads();
    for (int i = b0 + tid; i < b1; i += 512) {
        int d = dst[i];
        int s = src[i];
        bufRaw[i - b0] = make_int2(s, d);
        atomicAdd(&hist[d / NODES_PER_BUCKET], 1);
    }
    __syncthreads();
    if (tid < NBUCK) blkCntT[(size_t)g * NBUCK + tid] = hist[tid];
    __threadfence();
    grid.sync();

    // --- phase B: block g scans bucket g over chunks ---
    if (tid < NBUCK) sscan[tid] = blkCntT[(size_t)tid * NBUCK + g];
    __syncthreads();
    for (int off = 1; off < NBUCK; off <<= 1) {
        int u = (tid >= off && tid < NBUCK) ? sscan[tid - off] : 0;
        __syncthreads();
        if (tid < NBUCK) sscan[tid] += u;
        __syncthreads();
    }
    if (tid < NBUCK) {
        int v = blkCntT[(size_t)tid * NBUCK + g];
        blkBaseL[(size_t)g * NBUCK + tid] = sscan[tid] - v;   // [bucket=g? no]
    }
    // NOTE: here block g plays "bucket g": blkBaseL[g][chunk] layout below.
    if (tid == NBUCK - 1) bucketTotal[g] = sscan[NBUCK - 1];
    __threadfence();
    grid.sync();

    // --- phase C: block 0 scans bucket totals -> bstart ---
    if (g == 0) {
        if (tid < NBUCK) sscan[tid] = bucketTotal[tid];
        __syncthreads();
        for (int off = 1; off < NBUCK; off <<= 1) {
            int u = (tid >= off && tid < NBUCK) ? sscan[tid - off] : 0;
            __syncthreads();
            if (tid < NBUCK) sscan[tid] += u;
            __syncthreads();
        }
        if (tid < NBUCK) bstart[tid] = sscan[tid] - bucketTotal[tid];
        if (tid == NBUCK - 1) {
            bstart[NBUCK] = sscan[NBUCK - 1];
            offsets[N_NODES] = sscan[NBUCK - 1];
        }
        __threadfence();
    }
    grid.sync();

    // --- phase D: LDS-sort this chunk by bucket, write runs coalesced ---
    if (tid < NBUCK) sscan[tid] = hist[tid];
    __syncthreads();
    for (int off = 1; off < NBUCK; off <<= 1) {
        int u = (tid >= off && tid < NBUCK) ? sscan[tid - off] : 0;
        __syncthreads();
        if (tid < NBUCK) sscan[tid] += u;
        __syncthreads();
    }
    if (tid < NBUCK) {
        int v = hist[tid];
        runStart[tid] = sscan[tid] - v;
        cur[tid] = sscan[tid] - v;
        // bucket tid's base for chunk g: bstart + blkBaseL[bucket][chunk]
        gbase[tid] = bstart[tid] + blkBaseL[(size_t)tid * NBUCK + g];
    }
    __syncthreads();
    for (int i = tid; i < cnt; i += 512) {
        int2 e = bufRaw[i];
        int k = e.y / NODES_PER_BUCKET;
        int p = atomicAdd(&cur[k], 1);
        bufSrt[p] = e;
    }
    __syncthreads();
    for (int i = tid; i < cnt; i += 512) {
        int2 e = bufSrt[i];
        int k = e.y / NODES_PER_BUCKET;
        staging[gbase[k] + (i - runStart[k])] = e;
    }
    __threadfence();
    grid.sync();

    // --- phase E: block g = bucket g fill (overlay onto dead edge bufs) ---
    int* scnt  = (int*)smem;
    int* sexc  = (int*)(smem + 1600);
    int* scur  = (int*)(smem + 3200);
    int* ssrcL = (int*)(smem + 4800);   // 8192 ints

    const int node0 = g * NODES_PER_BUCKET;
    const int nn = min(node0 + NODES_PER_BUCKET, N_NODES) - node0;
    if (nn <= 0) return;
    const int es = bstart[g], ee = bstart[g + 1];
    const int ecnt = ee - es;

    for (int j = tid; j < nn; j += 512) scnt[j] = 0;
    __syncthreads();
    for (int i = es + tid; i < ee; i += 512) {
        int2 e = staging[i];
        atomicAdd(&scnt[e.y - node0], 1);
    }
    __syncthreads();

    if (tid < 64) {
        int base = tid * 7;
        int vals[7];
        int run = 0;
#pragma unroll
        for (int j = 0; j < 7; ++j) {
            int idx = base + j;
            int c = (idx < nn) ? scnt[idx] : 0;
            vals[j] = run;
            run += c;
        }
        int inc = run;
#pragma unroll
        for (int off = 1; off < 64; off <<= 1) {
            int u = __shfl_up(inc, off, 64);
            if (tid >= off) inc += u;
        }
        int laneExcl = inc - run;
#pragma unroll
        for (int j = 0; j < 7; ++j) {
            int idx = base + j;
            if (idx < nn) sexc[idx] = laneExcl + vals[j];
        }
    }
    __syncthreads();

    for (int j = tid; j < nn; j += 512) {
        int c = scnt[j];
        int ex = sexc[j];
        offsets[node0 + j] = es + ex;
        inv_deg[node0 + j] = 1.0f / (float)max(c, 1);
        scur[j] = ex;
    }
    __syncthreads();

    if (ecnt <= FILL_LDS_CAP) {
        for (int i = es + tid; i < ee; i += 512) {
            int2 e = staging[i];
            int p = atomicAdd(&scur[e.y - node0], 1);
            ssrcL[p] = e.x;
        }
        __syncthreads();
        for (int i = tid; i < ecnt; i += 512) ssrc[es + i] = ssrcL[i];
    } else {
        for (int i = es + tid; i < ee; i += 512) {
            int2 e = staging[i];
            int p = atomicAdd(&scur[e.y - node0], 1);
            ssrc[es + p] = e.x;
        }
    }
}

// ---------------- layer 1 fused: gather + linear (2 -> 128, bf16 out) ------

__global__ __launch_bounds__(256) void sage1_fused(const float* __restrict__ x,
                                                   const int* __restrict__ offs,
                                                   const int* __restrict__ ssrc,
                                                   const float* __restrict__ inv_deg,
                                                   const float* __restrict__ Wl,
                                                   const float* __restrict__ bl,
                                                   const float* __restrict__ Wr,
                                                   unsigned short* __restrict__ out_bf,
                                                   int nnodes) {
    int t = blockIdx.x * 256 + threadIdx.x;
    int node = t >> 2;
    int c = t & 3;
    if (node >= nnodes) return;
    // 4 lanes split the neighbor sum, shfl-combine (fp reorder only)
    const float2* __restrict__ x2 = (const float2*)x;
    int b = offs[node], e = offs[node + 1];
    float ax = 0.f, ay = 0.f;
    for (int i = b + c; i < e; i += 4) {
        float2 v = x2[ssrc[i]];
        ax += v.x;
        ay += v.y;
    }
    ax += __shfl_xor(ax, 1, 4);
    ay += __shfl_xor(ay, 1, 4);
    ax += __shfl_xor(ax, 2, 4);
    ay += __shfl_xor(ay, 2, 4);
    float s = inv_deg[node];
    ax *= s; ay *= s;
    float2 hh = x2[node];
    const float* wl0 = Wl + c * 32;
    const float* wl1 = Wl + 128 + c * 32;
    const float* wr0 = Wr + c * 32;
    const float* wr1 = Wr + 128 + c * 32;
    const float* bb = bl + c * 32;
    uint4* dst4 = (uint4*)(out_bf + (size_t)node * 128 + c * 32);
#pragma unroll
    for (int q = 0; q < 4; ++q) {
        unsigned vals[4];
#pragma unroll
        for (int pj = 0; pj < 4; ++pj) {
            int j = q * 8 + pj * 2;
            float v0 = fmaxf(bb[j] + ax * wl0[j] + ay * wl1[j] +
                             hh.x * wr0[j] + hh.y * wr1[j], 0.f);
            float v1 = fmaxf(bb[j + 1] + ax * wl0[j + 1] + ay * wl1[j + 1] +
                             hh.x * wr0[j + 1] + hh.y * wr1[j + 1], 0.f);
            vals[pj] = pack_bf(v0, v1);
        }
        dst4[q] = make_uint4(vals[0], vals[1], vals[2], vals[3]);
    }
}

// ---------------- aggregation (layer 2) ----------------

__global__ __launch_bounds__(256) void aggregate_bf128(const unsigned short* __restrict__ hb,
                                                       const int* __restrict__ offs,
                                                       const int* __restrict__ ssrc,
                                                       const float* __restrict__ inv_deg,
                                                       unsigned short* __restrict__ aggb,
                                                       int nnodes) {
    int t = blockIdx.x * 256 + threadIdx.x;
    if (t >= nnodes * 16) return;
    int node = t >> 4;
    int c = t & 15;
    int b = offs[node], e = offs[node + 1];
    const uint4* __restrict__ hb4 = (const uint4*)hb;
    float acc[8] = {0.f, 0.f, 0.f, 0.f, 0.f, 0.f, 0.f, 0.f};
    int i = b;
    for (; i + 4 <= e; i += 4) {
        uint4 p0 = hb4[(size_t)ssrc[i] * 16 + c];
        uint4 p1 = hb4[(size_t)ssrc[i + 1] * 16 + c];
        uint4 p2 = hb4[(size_t)ssrc[i + 2] * 16 + c];
        uint4 p3 = hb4[(size_t)ssrc[i + 3] * 16 + c];
        acc8_bf(acc, p0);
        acc8_bf(acc, p1);
        acc8_bf(acc, p2);
        acc8_bf(acc, p3);
    }
    for (; i < e; ++i) {
        uint4 p = hb4[(size_t)ssrc[i] * 16 + c];
        acc8_bf(acc, p);
    }
    float s = inv_deg[node];
    uint4 o;
    o.x = pack_bf(acc[0] * s, acc[1] * s);
    o.y = pack_bf(acc[2] * s, acc[3] * s);
    o.z = pack_bf(acc[4] * s, acc[5] * s);
    o.w = pack_bf(acc[6] * s, acc[7] * s);
    ((uint4*)aggb)[t] = o;
}

// ---------------- weight prep (single dispatch) ----------------

__global__ __launch_bounds__(256) void prep_all(const float* __restrict__ Wl2,
                                                const float* __restrict__ Wr2,
                                                const float* __restrict__ Wl3,
                                                const float* __restrict__ Wr3,
                                                const float* __restrict__ Wl4,
                                                const float* __restrict__ Wr4,
                                                const float* __restrict__ Wl5,
                                                const float* __restrict__ Wr5,
                                                unsigned short* __restrict__ Wt,
                                                unsigned short* __restrict__ W3c,
                                                unsigned short* __restrict__ W4c,
                                                unsigned short* __restrict__ W5c) {
    int idx = blockIdx.x * 256 + threadIdx.x;
    if (idx < 32768) {
        int n = idx >> 8, k = idx & 255;
        float v = (k < 128) ? Wl2[k * 128 + n] : Wr2[(k - 128) * 128 + n];
        Wt[idx] = f2bf_rne(v);
    } else if (idx < 32768 + 8192) {
        int j = idx - 32768;
        int n = j >> 7, k = j & 127;
        float v = (n < 32) ? Wl3[k * 32 + n] : Wr3[k * 32 + (n - 32)];
        W3c[j] = f2bf_rne(v);
    } else if (idx < 32768 + 8192 + 2048) {
        int j = idx - 32768 - 8192;
        int n = j >> 5, k = j & 31;
        float v = (n < 32) ? Wl4[k * 32 + n] : Wr4[k * 32 + (n - 32)];
        W4c[j] = f2bf_rne(v);
    } else if (idx < 32768 + 8192 + 4096) {
        int j = idx - 32768 - 8192 - 2048;
        int n = j >> 5, k = j & 31;
        float v = (n < 32) ? Wl5[k * 32 + n] : Wr5[k * 32 + (n - 32)];
        W5c[j] = f2bf_rne(v);
    }
}

// ---------------- layer-2 MFMA GEMM + fused layer-3 products ----------------

__global__ __launch_bounds__(256) void gemm_l2_mfma(const unsigned short* __restrict__ Ab,
                                                    const unsigned short* __restrict__ Hb,
                                                    const unsigned short* __restrict__ Wt,
                                                    const float* __restrict__ bias,
                                                    const unsigned short* __restrict__ W3c,
                                                    unsigned short* __restrict__ g3b,
                                                    float* __restrict__ p3, int M) {
    constexpr int BM = 128, BK = 64;
    __shared__ unsigned short smem[26112];
#define SA(r, c) smem[(r) * 72 + (c)]
#define SB(r, c) smem[9216 + (r) * 72 + (c)]
#define SH(r, c) smem[(r) * 136 + (c)]
#define SW3(r, c) smem[17408 + (r) * 136 + (c)]

    const int tid = threadIdx.x;
    const int m0 = blockIdx.x * BM;
    const int lane = tid & 63;
    const int wid = tid >> 6;
    const int l15 = lane & 15;
    const int quad = lane >> 4;
    const int wm = (wid >> 1) * 64;
    const int wn = (wid & 1) * 64;

    f32x4 acc[4][4];
#pragma unroll
    for (int i = 0; i < 4; ++i)
#pragma unroll
        for (int j = 0; j < 4; ++j) acc[i][j] = (f32x4){0.f, 0.f, 0.f, 0.f};

    for (int k0 = 0; k0 < 256; k0 += BK) {
        const uint4* __restrict__ srcA = (const uint4*)((k0 < 128) ? Ab : Hb);
        const int kc = (k0 & 64) >> 3;
#pragma unroll
        for (int l = 0; l < 4; ++l) {
            int idx = tid + l * 256;
            int row = idx >> 3;
            int c8 = idx & 7;
            int gr = min(m0 + row, M - 1);
            uint4 va = srcA[(size_t)gr * 16 + kc + c8];
            *(uint4*)&SA(row, c8 * 8) = va;
            uint4 vb = ((const uint4*)Wt)[(size_t)row * 32 + (k0 >> 3) + c8];
            *(uint4*)&SB(row, c8 * 8) = vb;
        }
        __syncthreads();

#pragma unroll
        for (int ks = 0; ks < BK; ks += 32) {
            bf16x8 a[4], b[4];
#pragma unroll
            for (int t = 0; t < 4; ++t) {
                a[t] = *(const bf16x8*)&SA(wm + t * 16 + l15, ks + quad * 8);
                b[t] = *(const bf16x8*)&SB(wn + t * 16 + l15, ks + quad * 8);
            }
#pragma unroll
            for (int i = 0; i < 4; ++i)
#pragma unroll
                for (int j = 0; j < 4; ++j)
                    acc[i][j] = __builtin_amdgcn_mfma_f32_16x16x32_bf16(
                        a[i], b[j], acc[i][j], 0, 0, 0);
        }
        __syncthreads();
    }

#pragma unroll
    for (int j = 0; j < 4; ++j) {
        int n = wn + j * 16 + l15;
        float bv = bias[n];
#pragma unroll
        for (int i = 0; i < 4; ++i) {
#pragma unroll
            for (int r = 0; r < 4; ++r) {
                int ml = wm + i * 16 + quad * 4 + r;
                SH(ml, n) = f2bf_rne(fmaxf(acc[i][j][r] + bv, 0.f));
            }
        }
    }
#pragma unroll
    for (int l = 0; l < 4; ++l) {
        int idx = tid + l * 256;
        int row = idx >> 4;
        int c8 = idx & 15;
        uint4 v = ((const uint4*)W3c)[(size_t)row * 16 + c8];
        *(uint4*)&SW3(row, c8 * 8) = v;
    }
    __syncthreads();

    f32x4 acc2[2][4];
#pragma unroll
    for (int i = 0; i < 2; ++i)
#pragma unroll
        for (int j = 0; j < 4; ++j) acc2[i][j] = (f32x4){0.f, 0.f, 0.f, 0.f};

#pragma unroll
    for (int ks = 0; ks < 128; ks += 32) {
        bf16x8 a[2], b[4];
#pragma unroll
        for (int i = 0; i < 2; ++i)
            a[i] = *(const bf16x8*)&SH(wid * 32 + i * 16 + l15, ks + quad * 8);
#pragma unroll
        for (int j = 0; j < 4; ++j)
            b[j] = *(const bf16x8*)&SW3(j * 16 + l15, ks + quad * 8);
#pragma unroll
        for (int i = 0; i < 2; ++i)
#pragma unroll
            for (int j = 0; j < 4; ++j)
                acc2[i][j] = __builtin_amdgcn_mfma_f32_16x16x32_bf16(
                    a[i], b[j], acc2[i][j], 0, 0, 0);
    }

#pragma unroll
    for (int i = 0; i < 2; ++i) {
#pragma unroll
        for (int r = 0; r < 4; ++r) {
            int m = m0 + wid * 32 + i * 16 + quad * 4 + r;
            if (m >= M) continue;
#pragma unroll
            for (int j = 0; j < 4; ++j) {
                float v = acc2[i][j][r];
                if (j < 2) g3b[(size_t)m * 32 + j * 16 + l15] = f2bf_rne(v);
                else       p3[(size_t)m * 32 + (j - 2) * 16 + l15] = v;
            }
        }
    }
#undef SA
#undef SB
#undef SH
#undef SW3
}

// ---------------- fused gather + combine + next-layer products --------------

__global__ __launch_bounds__(256) void aggregate_combine32(
        const unsigned short* __restrict__ gb_prev,
        const int* __restrict__ offs,
        const int* __restrict__ ssrc,
        const float* __restrict__ inv_deg,
        const float* __restrict__ p,
        const float* __restrict__ bias,
        const unsigned short* __restrict__ Wc,
        unsigned short* __restrict__ g_next,
        float* __restrict__ p_next, int nnodes) {
    __shared__ unsigned short hB[64][40];
    __shared__ unsigned short wB[64][40];

    const int tid = threadIdx.x;
    const int node0 = blockIdx.x * 64;
    const int node = node0 + (tid >> 2);
    const int c = tid & 3;
    const int ln = tid >> 2;

#pragma unroll
    for (int l = 0; l < 2; ++l) {
        int id = tid + l * 256;
        int r = id >> 3, cc = id & 7;
        uint2 v = ((const uint2*)Wc)[(size_t)r * 8 + cc];
        *(uint2*)&wB[r][cc * 4] = v;
    }

    uint4 hout = make_uint4(0u, 0u, 0u, 0u);
    if (node < nnodes) {
        int b = offs[node], e = offs[node + 1];
        const uint4* __restrict__ hb4 = (const uint4*)gb_prev;
        float acc[8] = {0.f, 0.f, 0.f, 0.f, 0.f, 0.f, 0.f, 0.f};
        int i = b;
        for (; i + 4 <= e; i += 4) {
            uint4 p0 = hb4[(size_t)ssrc[i] * 4 + c];
            uint4 p1 = hb4[(size_t)ssrc[i + 1] * 4 + c];
            uint4 p2 = hb4[(size_t)ssrc[i + 2] * 4 + c];
            uint4 p3 = hb4[(size_t)ssrc[i + 3] * 4 + c];
            acc8_bf(acc, p0);
            acc8_bf(acc, p1);
            acc8_bf(acc, p2);
            acc8_bf(acc, p3);
        }
        for (; i < e; ++i) acc8_bf(acc, hb4[(size_t)ssrc[i] * 4 + c]);
        float s = inv_deg[node];
        const float4* prow = (const float4*)(p + (size_t)node * 32 + c * 8);
        float4 p0 = prow[0], p1 = prow[1];
        const float* bb = bias + c * 8;
        float h0 = fmaxf(acc[0] * s + p0.x + bb[0], 0.f);
        float h1 = fmaxf(acc[1] * s + p0.y + bb[1], 0.f);
        float h2 = fmaxf(acc[2] * s + p0.z + bb[2], 0.f);
        float h3 = fmaxf(acc[3] * s + p0.w + bb[3], 0.f);
        float h4 = fmaxf(acc[4] * s + p1.x + bb[4], 0.f);
        float h5 = fmaxf(acc[5] * s + p1.y + bb[5], 0.f);
        float h6 = fmaxf(acc[6] * s + p1.z + bb[6], 0.f);
        float h7 = fmaxf(acc[7] * s + p1.w + bb[7], 0.f);
        hout.x = pack_bf(h0, h1);
        hout.y = pack_bf(h2, h3);
        hout.z = pack_bf(h4, h5);
        hout.w = pack_bf(h6, h7);
    }
    *(uint4*)&hB[ln][c * 8] = hout;
    __syncthreads();

    const int lane = tid & 63;
    const int wid = tid >> 6;
    const int l15 = lane & 15;
    const int quad = lane >> 4;

    bf16x8 a = *(const bf16x8*)&hB[wid * 16 + l15][quad * 8];
    f32x4 accm[4];
#pragma unroll
    for (int j = 0; j < 4; ++j) {
        bf16x8 b = *(const bf16x8*)&wB[j * 16 + l15][quad * 8];
        accm[j] = __builtin_amdgcn_mfma_f32_16x16x32_bf16(
            a, b, (f32x4){0.f, 0.f, 0.f, 0.f}, 0, 0, 0);
    }

#pragma unroll
    for (int r = 0; r < 4; ++r) {
        int m = node0 + wid * 16 + quad * 4 + r;
        if (m >= nnodes) continue;
#pragma unroll
        for (int j = 0; j < 4; ++j) {
            float v = accm[j][r];
            if (j < 2) g_next[(size_t)m * 32 + j * 16 + l15] = f2bf_rne(v);
            else       p_next[(size_t)m * 32 + (j - 2) * 16 + l15] = v;
        }
    }
}

// fused gather + layer-5 finish + output projection
__global__ __launch_bounds__(256) void aggregate_final32(
        const unsigned short* __restrict__ gb_prev,
        const int* __restrict__ offs,
        const int* __restrict__ ssrc,
        const float* __restrict__ inv_deg,
        const float* __restrict__ p,
        const float* __restrict__ bias,
        const float* __restrict__ Wout,
        const float* __restrict__ bout,
        float* __restrict__ out, int nnodes) {
    int t = blockIdx.x * 256 + threadIdx.x;
    int node = t >> 2;
    int c = t & 3;
    if (node >= nnodes) return;
    int b = offs[node], e = offs[node + 1];
    const uint4* __restrict__ hb4 = (const uint4*)gb_prev;
    float acc[8] = {0.f, 0.f, 0.f, 0.f, 0.f, 0.f, 0.f, 0.f};
    int i = b;
    for (; i + 4 <= e; i += 4) {
        uint4 p0 = hb4[(size_t)ssrc[i] * 4 + c];
        uint4 p1 = hb4[(size_t)ssrc[i + 1] * 4 + c];
        uint4 p2 = hb4[(size_t)ssrc[i + 2] * 4 + c];
        uint4 p3 = hb4[(size_t)ssrc[i + 3] * 4 + c];
        acc8_bf(acc, p0);
        acc8_bf(acc, p1);
        acc8_bf(acc, p2);
        acc8_bf(acc, p3);
    }
    for (; i < e; ++i) acc8_bf(acc, hb4[(size_t)ssrc[i] * 4 + c]);
    float s = inv_deg[node];
    const float4* prow = (const float4*)(p + (size_t)node * 32 + c * 8);
    float4 p0 = prow[0], p1 = prow[1];
    const float* bb = bias + c * 8;
    const float* w = Wout + c * 8;
    float sum = 0.f;
    sum = fmaf(fmaxf(acc[0] * s + p0.x + bb[0], 0.f), w[0], sum);
    sum = fmaf(fmaxf(acc[1] * s + p0.y + bb[1], 0.f), w[1], sum);
    sum = fmaf(fmaxf(acc[2] * s + p0.z + bb[2], 0.f), w[2], sum);
    sum = fmaf(fmaxf(acc[3] * s + p0.w + bb[3], 0.f), w[3], sum);
    sum = fmaf(fmaxf(acc[4] * s + p1.x + bb[4], 0.f), w[4], sum);
    sum = fmaf(fmaxf(acc[5] * s + p1.y + bb[5], 0.f), w[5], sum);
    sum = fmaf(fmaxf(acc[6] * s + p1.z + bb[6], 0.f), w[6], sum);
    sum = fmaf(fmaxf(acc[7] * s + p1.w + bb[7], 0.f), w[7], sum);
    sum += __shfl_down(sum, 2, 4);
    sum += __shfl_down(sum, 1, 4);
    if (c == 0) out[node] = sum + bout[0];
}

// ---------------- launch ----------------

extern "C" void kernel_launch(void* const* d_in, const int* in_sizes, int n_in,
                              void* d_out, int out_size, void* d_ws, size_t ws_size,
                              hipStream_t stream) {
    const float* x      = (const float*)d_in[0];
    const int*   ei     = (const int*)d_in[1];
    const float* Wl1    = (const float*)d_in[3];
    const float* bl1    = (const float*)d_in[4];
    const float* Wr1    = (const float*)d_in[5];
    const float* Wl2    = (const float*)d_in[6];
    const float* bl2    = (const float*)d_in[7];
    const float* Wr2    = (const float*)d_in[8];
    const float* Wl3    = (const float*)d_in[9];
    const float* bl3    = (const float*)d_in[10];
    const float* Wr3    = (const float*)d_in[11];
    const float* Wl4    = (const float*)d_in[12];
    const float* bl4    = (const float*)d_in[13];
    const float* Wr4    = (const float*)d_in[14];
    const float* Wl5    = (const float*)d_in[15];
    const float* bl5    = (const float*)d_in[16];
    const float* Wr5    = (const float*)d_in[17];
    const float* W_out  = (const float*)d_in[18];
    const float* b_out  = (const float*)d_in[19];
    float* out = (float*)d_out;

    const int N = N_NODES, E = N_EDGES;
    const int* e_src = ei;
    const int* e_dst = ei + E;

    size_t off = 0;
    auto carve = [&](size_t bytes) {
        void* p = (char*)d_ws + off;
        off += (bytes + 255) & ~(size_t)255;
        return p;
    };
    int*   offsets  = (int*)carve((size_t)(N + 1) * 4);
    float* inv_deg  = (float*)carve((size_t)N * 4);
    int*   ssrc     = (int*)carve((size_t)E * 4);
    int*   blkCntT  = (int*)carve((size_t)NBUCK * NBUCK * 4);
    int*   blkBaseL = (int*)carve((size_t)NBUCK * NBUCK * 4);
    int*   bucketTotal = (int*)carve((size_t)NBUCK * 4);
    int*   bstart   = (int*)carve((size_t)(NBUCK + 1) * 4);
    int2*  staging  = (int2*)carve((size_t)E * 8);
    unsigned short* Wt  = (unsigned short*)carve((size_t)128 * 256 * 2);
    unsigned short* W3c = (unsigned short*)carve((size_t)64 * 128 * 2);
    unsigned short* W4c = (unsigned short*)carve((size_t)64 * 32 * 2);
    unsigned short* W5c = (unsigned short*)carve((size_t)64 * 32 * 2);
    float* agg      = (float*)carve((size_t)N * 128 * 4);
    float* bufA     = (float*)carve((size_t)N * 128 * 4);
    unsigned short* g3b = (unsigned short*)carve((size_t)N * 32 * 2);
    unsigned short* g4b = (unsigned short*)carve((size_t)N * 32 * 2);
    unsigned short* g5b = (unsigned short*)carve((size_t)N * 32 * 2);

    float* slotA = agg;                       // p3 / p5
    float* slotC = agg + (size_t)N * 64;      // p4
    unsigned short* h1_bf = (unsigned short*)bufA;
    unsigned short* aggB  = (unsigned short*)bufA + (size_t)N * 128;

    // --- CSR build: single cooperative kernel ---
    {
        void* kargs[] = {(void*)&e_src, (void*)&e_dst, (void*)&blkCntT,
                         (void*)&blkBaseL, (void*)&bucketTotal, (void*)&bstart,
                         (void*)&staging, (void*)&ssrc, (void*)&offsets,
                         (void*)&inv_deg};
        hipLaunchCooperativeKernel((void*)csr_coop, dim3(NBUCK), dim3(512),
                                   kargs, 0, stream);
    }
    prep_all<<<176, 256, 0, stream>>>(Wl2, Wr2, Wl3, Wr3, Wl4, Wr4, Wl5, Wr5,
                                      Wt, W3c, W4c, W5c);

    const int gemm_grid = (N + 127) / 128;
    const int comb_grid = (N + 63) / 64;

    // --- layer 1: fused gather + linear (bf16 out) ---
    sage1_fused<<<(N * 4 + 255) / 256, 256, 0, stream>>>(x, offsets, ssrc, inv_deg,
                                                         Wl1, bl1, Wr1, h1_bf, N);

    // --- layer 2 + layer-3 products ---
    aggregate_bf128<<<(N * 16 + 255) / 256, 256, 0, stream>>>(h1_bf, offsets, ssrc,
                                                              inv_deg, aggB, N);
    gemm_l2_mfma<<<gemm_grid, 256, 0, stream>>>(aggB, h1_bf, Wt, bl2, W3c, g3b, slotA, N);

    // --- layer 3 finish + layer-4 products ---
    aggregate_combine32<<<comb_grid, 256, 0, stream>>>(g3b, offsets, ssrc, inv_deg,
                                                       slotA, bl3, W4c, g4b, slotC, N);

    // --- layer 4 finish + layer-5 products ---
    aggregate_combine32<<<comb_grid, 256, 0, stream>>>(g4b, offsets, ssrc, inv_deg,
                                                       slotC, bl4, W5c, g5b, slotA, N);

    // --- layer 5 finish + output projection ---
    aggregate_final32<<<(N * 4 + 255) / 256, 256, 0, stream>>>(g5b, offsets, ssrc, inv_deg,
                                                               slotA, bl5, W_out, b_out,
                                                               out, N);
}

// Round 19
// 348.162 us; speedup vs baseline: 1.7013x; 1.7013x over previous
//
#include <hip/hip_runtime.h>
#include <hip/hip_bf16.h>

#define N_NODES 100000
#define N_EDGES 1600000
#define NBUCK 256
#define NODES_PER_BUCKET 391        // 256*391 = 100096 >= 100000
#define EDGES_PER_CHUNK (N_EDGES / NBUCK)   // 6250 exactly
#define FILL_LDS_CAP 8192           // mean 6250, sigma~79 -> +24 sigma

typedef __bf16 bf16x8 __attribute__((ext_vector_type(8)));
typedef float f32x4 __attribute__((ext_vector_type(4)));

// ---------------- helpers ----------------

__device__ inline unsigned short f2bf_rne(float v) {
    unsigned u = __float_as_uint(v);
    u += 0x7fffu + ((u >> 16) & 1u);
    return (unsigned short)(u >> 16);
}

__device__ inline unsigned pack_bf(float a, float b) {
    return (unsigned)f2bf_rne(a) | ((unsigned)f2bf_rne(b) << 16);
}

__device__ inline void acc8_bf(float* a, uint4 p) {
    a[0] += __uint_as_float(p.x << 16);
    a[1] += __uint_as_float(p.x & 0xffff0000u);
    a[2] += __uint_as_float(p.y << 16);
    a[3] += __uint_as_float(p.y & 0xffff0000u);
    a[4] += __uint_as_float(p.z << 16);
    a[5] += __uint_as_float(p.z & 0xffff0000u);
    a[6] += __uint_as_float(p.w << 16);
    a[7] += __uint_as_float(p.w & 0xffff0000u);
}

// ---------------- CSR build: 256-bucket counting sort (split, R17) ---------
// R18 post-mortem: cooperative fusion of these phases costs 251us (grid.sync
// via device-scope atomics across 8 XCDs >> kernel-launch boundaries). Keep
// the 5-kernel split.

__global__ __launch_bounds__(256) void pa_count(const int* __restrict__ dst,
                                                int* __restrict__ blkCntT) {
    __shared__ int hist[NBUCK];
    hist[threadIdx.x] = 0;
    __syncthreads();
    int b0 = blockIdx.x * EDGES_PER_CHUNK;
    int b1 = min(b0 + EDGES_PER_CHUNK, N_EDGES);
    for (int i = b0 + (int)threadIdx.x; i < b1; i += 256) {
        int d = __builtin_nontemporal_load(&dst[i]);
        atomicAdd(&hist[d / NODES_PER_BUCKET], 1);
    }
    __syncthreads();
    blkCntT[threadIdx.x * NBUCK + blockIdx.x] = hist[threadIdx.x];
}

__global__ __launch_bounds__(256) void pa_scan1(const int* __restrict__ blkCntT,
                                                int* __restrict__ blkBaseL,
                                                int* __restrict__ bucketTotal) {
    __shared__ int s[256];
    int t = threadIdx.x;
    int v = blkCntT[blockIdx.x * NBUCK + t];
    s[t] = v;
    __syncthreads();
    for (int off = 1; off < 256; off <<= 1) {
        int u = (t >= off) ? s[t - off] : 0;
        __syncthreads();
        s[t] += u;
        __syncthreads();
    }
    blkBaseL[blockIdx.x * NBUCK + t] = s[t] - v;
    if (t == 255) bucketTotal[blockIdx.x] = s[255];
}

__global__ __launch_bounds__(256) void pa_scan2(const int* __restrict__ bucketTotal,
                                                int* __restrict__ bstart,
                                                int* __restrict__ offsets) {
    __shared__ int s[256];
    int t = threadIdx.x;
    int v = bucketTotal[t];
    s[t] = v;
    __syncthreads();
    for (int off = 1; off < 256; off <<= 1) {
        int u = (t >= off) ? s[t - off] : 0;
        __syncthreads();
        s[t] += u;
        __syncthreads();
    }
    bstart[t] = s[t] - v;
    if (t == 255) {
        bstart[256] = s[255];
        offsets[N_NODES] = s[255];
    }
}

__global__ __launch_bounds__(256) void pa_scatter(const int* __restrict__ src,
                                                  const int* __restrict__ dst,
                                                  const int* __restrict__ blkCntT,
                                                  const int* __restrict__ blkBaseL,
                                                  const int* __restrict__ bstart,
                                                  int2* __restrict__ staging) {
    __shared__ int runStart[NBUCK];
    __shared__ int cur[NBUCK];
    __shared__ int gbase[NBUCK];
    __shared__ int2 buf[EDGES_PER_CHUNK];

    const int tid = threadIdx.x;
    const int g = blockIdx.x;
    const int b0 = g * EDGES_PER_CHUNK;
    const int b1 = min(b0 + EDGES_PER_CHUNK, N_EDGES);

    {
        __shared__ int s[256];
        int v = blkCntT[tid * NBUCK + g];
        s[tid] = v;
        __syncthreads();
        for (int off = 1; off < 256; off <<= 1) {
            int u = (tid >= off) ? s[tid - off] : 0;
            __syncthreads();
            s[tid] += u;
            __syncthreads();
        }
        runStart[tid] = s[tid] - v;
        cur[tid] = s[tid] - v;
        gbase[tid] = bstart[tid] + blkBaseL[tid * NBUCK + g];
    }
    __syncthreads();
    for (int i = b0 + tid; i < b1; i += 256) {
        int d = __builtin_nontemporal_load(&dst[i]);
        int s_ = __builtin_nontemporal_load(&src[i]);
        int k = d / NODES_PER_BUCKET;
        int p = atomicAdd(&cur[k], 1);
        buf[p] = make_int2(s_, d);
    }
    __syncthreads();
    int cnt = b1 - b0;
    for (int i = tid; i < cnt; i += 256) {
        int2 e = buf[i];
        int k = e.y / NODES_PER_BUCKET;
        staging[gbase[k] + (i - runStart[k])] = e;
    }
}

__global__ __launch_bounds__(512) void pc_fill(const int2* __restrict__ staging,
                                               const int* __restrict__ bstart,
                                               int* __restrict__ ssrc,
                                               int* __restrict__ offsets,
                                               float* __restrict__ inv_deg) {
    __shared__ int scnt[NODES_PER_BUCKET];
    __shared__ int sexc[NODES_PER_BUCKET];
    __shared__ int scur[NODES_PER_BUCKET];
    __shared__ int ssrcL[FILL_LDS_CAP];

    const int tid = threadIdx.x;
    const int b = blockIdx.x;
    const int node0 = b * NODES_PER_BUCKET;
    const int nn = min(node0 + NODES_PER_BUCKET, N_NODES) - node0;
    if (nn <= 0) return;
    const int es = bstart[b], ee = bstart[b + 1];
    const int cnt = ee - es;

    for (int j = tid; j < nn; j += 512) scnt[j] = 0;
    __syncthreads();
    for (int i = es + tid; i < ee; i += 512) {
        int2 e = staging[i];
        atomicAdd(&scnt[e.y - node0], 1);
    }
    __syncthreads();

    if (tid < 64) {
        int base = tid * 7;
        int vals[7];
        int run = 0;
#pragma unroll
        for (int j = 0; j < 7; ++j) {
            int idx = base + j;
            int c = (idx < nn) ? scnt[idx] : 0;
            vals[j] = run;
            run += c;
        }
        int inc = run;
#pragma unroll
        for (int off = 1; off < 64; off <<= 1) {
            int u = __shfl_up(inc, off, 64);
            if (tid >= off) inc += u;
        }
        int laneExcl = inc - run;
#pragma unroll
        for (int j = 0; j < 7; ++j) {
            int idx = base + j;
            if (idx < nn) sexc[idx] = laneExcl + vals[j];
        }
    }
    __syncthreads();

    for (int j = tid; j < nn; j += 512) {
        int c = scnt[j];
        int ex = sexc[j];
        offsets[node0 + j] = es + ex;
        inv_deg[node0 + j] = 1.0f / (float)max(c, 1);
        scur[j] = ex;
    }
    __syncthreads();

    if (cnt <= FILL_LDS_CAP) {
        for (int i = es + tid; i < ee; i += 512) {
            int2 e = staging[i];
            int p = atomicAdd(&scur[e.y - node0], 1);
            ssrcL[p] = e.x;
        }
        __syncthreads();
        for (int i = tid; i < cnt; i += 512) ssrc[es + i] = ssrcL[i];
    } else {
        for (int i = es + tid; i < ee; i += 512) {
            int2 e = staging[i];
            int p = atomicAdd(&scur[e.y - node0], 1);
            ssrc[es + p] = e.x;
        }
    }
}

// ---------------- layer 1 fused: gather + linear (2 -> 128, bf16 out) ------

__global__ __launch_bounds__(256) void sage1_fused(const float* __restrict__ x,
                                                   const int* __restrict__ offs,
                                                   const int* __restrict__ ssrc,
                                                   const float* __restrict__ inv_deg,
                                                   const float* __restrict__ Wl,
                                                   const float* __restrict__ bl,
                                                   const float* __restrict__ Wr,
                                                   unsigned short* __restrict__ out_bf,
                                                   int nnodes) {
    int t = blockIdx.x * 256 + threadIdx.x;
    int node = t >> 2;
    int c = t & 3;
    if (node >= nnodes) return;
    const float2* __restrict__ x2 = (const float2*)x;
    int b = offs[node], e = offs[node + 1];
    float ax = 0.f, ay = 0.f;
    for (int i = b + c; i < e; i += 4) {
        float2 v = x2[ssrc[i]];
        ax += v.x;
        ay += v.y;
    }
    ax += __shfl_xor(ax, 1, 4);
    ay += __shfl_xor(ay, 1, 4);
    ax += __shfl_xor(ax, 2, 4);
    ay += __shfl_xor(ay, 2, 4);
    float s = inv_deg[node];
    ax *= s; ay *= s;
    float2 hh = x2[node];
    const float* wl0 = Wl + c * 32;
    const float* wl1 = Wl + 128 + c * 32;
    const float* wr0 = Wr + c * 32;
    const float* wr1 = Wr + 128 + c * 32;
    const float* bb = bl + c * 32;
    uint4* dst4 = (uint4*)(out_bf + (size_t)node * 128 + c * 32);
#pragma unroll
    for (int q = 0; q < 4; ++q) {
        unsigned vals[4];
#pragma unroll
        for (int pj = 0; pj < 4; ++pj) {
            int j = q * 8 + pj * 2;
            float v0 = fmaxf(bb[j] + ax * wl0[j] + ay * wl1[j] +
                             hh.x * wr0[j] + hh.y * wr1[j], 0.f);
            float v1 = fmaxf(bb[j + 1] + ax * wl0[j + 1] + ay * wl1[j + 1] +
                             hh.x * wr0[j + 1] + hh.y * wr1[j + 1], 0.f);
            vals[pj] = pack_bf(v0, v1);
        }
        dst4[q] = make_uint4(vals[0], vals[1], vals[2], vals[3]);
    }
}

// ---------------- aggregation (layer 2) ----------------

__global__ __launch_bounds__(256) void aggregate_bf128(const unsigned short* __restrict__ hb,
                                                       const int* __restrict__ offs,
                                                       const int* __restrict__ ssrc,
                                                       const float* __restrict__ inv_deg,
                                                       unsigned short* __restrict__ aggb,
                                                       int nnodes) {
    int t = blockIdx.x * 256 + threadIdx.x;
    if (t >= nnodes * 16) return;
    int node = t >> 4;
    int c = t & 15;
    int b = offs[node], e = offs[node + 1];
    const uint4* __restrict__ hb4 = (const uint4*)hb;
    float acc[8] = {0.f, 0.f, 0.f, 0.f, 0.f, 0.f, 0.f, 0.f};
    int i = b;
    for (; i + 4 <= e; i += 4) {
        uint4 p0 = hb4[(size_t)ssrc[i] * 16 + c];
        uint4 p1 = hb4[(size_t)ssrc[i + 1] * 16 + c];
        uint4 p2 = hb4[(size_t)ssrc[i + 2] * 16 + c];
        uint4 p3 = hb4[(size_t)ssrc[i + 3] * 16 + c];
        acc8_bf(acc, p0);
        acc8_bf(acc, p1);
        acc8_bf(acc, p2);
        acc8_bf(acc, p3);
    }
    for (; i < e; ++i) {
        uint4 p = hb4[(size_t)ssrc[i] * 16 + c];
        acc8_bf(acc, p);
    }
    float s = inv_deg[node];
    uint4 o;
    o.x = pack_bf(acc[0] * s, acc[1] * s);
    o.y = pack_bf(acc[2] * s, acc[3] * s);
    o.z = pack_bf(acc[4] * s, acc[5] * s);
    o.w = pack_bf(acc[6] * s, acc[7] * s);
    ((uint4*)aggb)[t] = o;
}

// ---------------- weight prep (single dispatch) ----------------

__global__ __launch_bounds__(256) void prep_all(const float* __restrict__ Wl2,
                                                const float* __restrict__ Wr2,
                                                const float* __restrict__ Wl3,
                                                const float* __restrict__ Wr3,
                                                const float* __restrict__ Wl4,
                                                const float* __restrict__ Wr4,
                                                const float* __restrict__ Wl5,
                                                const float* __restrict__ Wr5,
                                                unsigned short* __restrict__ Wt,
                                                unsigned short* __restrict__ W3c,
                                                unsigned short* __restrict__ W4c,
                                                unsigned short* __restrict__ W5c) {
    int idx = blockIdx.x * 256 + threadIdx.x;
    if (idx < 32768) {
        int n = idx >> 8, k = idx & 255;
        float v = (k < 128) ? Wl2[k * 128 + n] : Wr2[(k - 128) * 128 + n];
        Wt[idx] = f2bf_rne(v);
    } else if (idx < 32768 + 8192) {
        int j = idx - 32768;
        int n = j >> 7, k = j & 127;
        float v = (n < 32) ? Wl3[k * 32 + n] : Wr3[k * 32 + (n - 32)];
        W3c[j] = f2bf_rne(v);
    } else if (idx < 32768 + 8192 + 2048) {
        int j = idx - 32768 - 8192;
        int n = j >> 5, k = j & 31;
        float v = (n < 32) ? Wl4[k * 32 + n] : Wr4[k * 32 + (n - 32)];
        W4c[j] = f2bf_rne(v);
    } else if (idx < 32768 + 8192 + 4096) {
        int j = idx - 32768 - 8192 - 2048;
        int n = j >> 5, k = j & 31;
        float v = (n < 32) ? Wl5[k * 32 + n] : Wr5[k * 32 + (n - 32)];
        W5c[j] = f2bf_rne(v);
    }
}

// ---------------- layer-2 MFMA GEMM + fused layer-3 products ----------------

__global__ __launch_bounds__(256) void gemm_l2_mfma(const unsigned short* __restrict__ Ab,
                                                    const unsigned short* __restrict__ Hb,
                                                    const unsigned short* __restrict__ Wt,
                                                    const float* __restrict__ bias,
                                                    const unsigned short* __restrict__ W3c,
                                                    unsigned short* __restrict__ g3b,
                                                    float* __restrict__ p3, int M) {
    constexpr int BM = 128, BK = 64;
    __shared__ unsigned short smem[26112];
#define SA(r, c) smem[(r) * 72 + (c)]
#define SB(r, c) smem[9216 + (r) * 72 + (c)]
#define SH(r, c) smem[(r) * 136 + (c)]
#define SW3(r, c) smem[17408 + (r) * 136 + (c)]

    const int tid = threadIdx.x;
    const int m0 = blockIdx.x * BM;
    const int lane = tid & 63;
    const int wid = tid >> 6;
    const int l15 = lane & 15;
    const int quad = lane >> 4;
    const int wm = (wid >> 1) * 64;
    const int wn = (wid & 1) * 64;

    f32x4 acc[4][4];
#pragma unroll
    for (int i = 0; i < 4; ++i)
#pragma unroll
        for (int j = 0; j < 4; ++j) acc[i][j] = (f32x4){0.f, 0.f, 0.f, 0.f};

    for (int k0 = 0; k0 < 256; k0 += BK) {
        const uint4* __restrict__ srcA = (const uint4*)((k0 < 128) ? Ab : Hb);
        const int kc = (k0 & 64) >> 3;
#pragma unroll
        for (int l = 0; l < 4; ++l) {
            int idx = tid + l * 256;
            int row = idx >> 3;
            int c8 = idx & 7;
            int gr = min(m0 + row, M - 1);
            uint4 va = srcA[(size_t)gr * 16 + kc + c8];
            *(uint4*)&SA(row, c8 * 8) = va;
            uint4 vb = ((const uint4*)Wt)[(size_t)row * 32 + (k0 >> 3) + c8];
            *(uint4*)&SB(row, c8 * 8) = vb;
        }
        __syncthreads();

#pragma unroll
        for (int ks = 0; ks < BK; ks += 32) {
            bf16x8 a[4], b[4];
#pragma unroll
            for (int t = 0; t < 4; ++t) {
                a[t] = *(const bf16x8*)&SA(wm + t * 16 + l15, ks + quad * 8);
                b[t] = *(const bf16x8*)&SB(wn + t * 16 + l15, ks + quad * 8);
            }
#pragma unroll
            for (int i = 0; i < 4; ++i)
#pragma unroll
                for (int j = 0; j < 4; ++j)
                    acc[i][j] = __builtin_amdgcn_mfma_f32_16x16x32_bf16(
                        a[i], b[j], acc[i][j], 0, 0, 0);
        }
        __syncthreads();
    }

#pragma unroll
    for (int j = 0; j < 4; ++j) {
        int n = wn + j * 16 + l15;
        float bv = bias[n];
#pragma unroll
        for (int i = 0; i < 4; ++i) {
#pragma unroll
            for (int r = 0; r < 4; ++r) {
                int ml = wm + i * 16 + quad * 4 + r;
                SH(ml, n) = f2bf_rne(fmaxf(acc[i][j][r] + bv, 0.f));
            }
        }
    }
#pragma unroll
    for (int l = 0; l < 4; ++l) {
        int idx = tid + l * 256;
        int row = idx >> 4;
        int c8 = idx & 15;
        uint4 v = ((const uint4*)W3c)[(size_t)row * 16 + c8];
        *(uint4*)&SW3(row, c8 * 8) = v;
    }
    __syncthreads();

    f32x4 acc2[2][4];
#pragma unroll
    for (int i = 0; i < 2; ++i)
#pragma unroll
        for (int j = 0; j < 4; ++j) acc2[i][j] = (f32x4){0.f, 0.f, 0.f, 0.f};

#pragma unroll
    for (int ks = 0; ks < 128; ks += 32) {
        bf16x8 a[2], b[4];
#pragma unroll
        for (int i = 0; i < 2; ++i)
            a[i] = *(const bf16x8*)&SH(wid * 32 + i * 16 + l15, ks + quad * 8);
#pragma unroll
        for (int j = 0; j < 4; ++j)
            b[j] = *(const bf16x8*)&SW3(j * 16 + l15, ks + quad * 8);
#pragma unroll
        for (int i = 0; i < 2; ++i)
#pragma unroll
            for (int j = 0; j < 4; ++j)
                acc2[i][j] = __builtin_amdgcn_mfma_f32_16x16x32_bf16(
                    a[i], b[j], acc2[i][j], 0, 0, 0);
    }

#pragma unroll
    for (int i = 0; i < 2; ++i) {
#pragma unroll
        for (int r = 0; r < 4; ++r) {
            int m = m0 + wid * 32 + i * 16 + quad * 4 + r;
            if (m >= M) continue;
#pragma unroll
            for (int j = 0; j < 4; ++j) {
                float v = acc2[i][j][r];
                if (j < 2) g3b[(size_t)m * 32 + j * 16 + l15] = f2bf_rne(v);
                else       p3[(size_t)m * 32 + (j - 2) * 16 + l15] = v;
            }
        }
    }
#undef SA
#undef SB
#undef SH
#undef SW3
}

// ---------------- fused gather + combine + next-layer products --------------

__global__ __launch_bounds__(256) void aggregate_combine32(
        const unsigned short* __restrict__ gb_prev,
        const int* __restrict__ offs,
        const int* __restrict__ ssrc,
        const float* __restrict__ inv_deg,
        const float* __restrict__ p,
        const float* __restrict__ bias,
        const unsigned short* __restrict__ Wc,
        unsigned short* __restrict__ g_next,
        float* __restrict__ p_next, int nnodes) {
    __shared__ unsigned short hB[64][40];
    __shared__ unsigned short wB[64][40];

    const int tid = threadIdx.x;
    const int node0 = blockIdx.x * 64;
    const int node = node0 + (tid >> 2);
    const int c = tid & 3;
    const int ln = tid >> 2;

#pragma unroll
    for (int l = 0; l < 2; ++l) {
        int id = tid + l * 256;
        int r = id >> 3, cc = id & 7;
        uint2 v = ((const uint2*)Wc)[(size_t)r * 8 + cc];
        *(uint2*)&wB[r][cc * 4] = v;
    }

    uint4 hout = make_uint4(0u, 0u, 0u, 0u);
    if (node < nnodes) {
        int b = offs[node], e = offs[node + 1];
        const uint4* __restrict__ hb4 = (const uint4*)gb_prev;
        float acc[8] = {0.f, 0.f, 0.f, 0.f, 0.f, 0.f, 0.f, 0.f};
        int i = b;
        for (; i + 4 <= e; i += 4) {
            uint4 p0 = hb4[(size_t)ssrc[i] * 4 + c];
            uint4 p1 = hb4[(size_t)ssrc[i + 1] * 4 + c];
            uint4 p2 = hb4[(size_t)ssrc[i + 2] * 4 + c];
            uint4 p3 = hb4[(size_t)ssrc[i + 3] * 4 + c];
            acc8_bf(acc, p0);
            acc8_bf(acc, p1);
            acc8_bf(acc, p2);
            acc8_bf(acc, p3);
        }
        for (; i < e; ++i) acc8_bf(acc, hb4[(size_t)ssrc[i] * 4 + c]);
        float s = inv_deg[node];
        const float4* prow = (const float4*)(p + (size_t)node * 32 + c * 8);
        float4 p0 = prow[0], p1 = prow[1];
        const float* bb = bias + c * 8;
        float h0 = fmaxf(acc[0] * s + p0.x + bb[0], 0.f);
        float h1 = fmaxf(acc[1] * s + p0.y + bb[1], 0.f);
        float h2 = fmaxf(acc[2] * s + p0.z + bb[2], 0.f);
        float h3 = fmaxf(acc[3] * s + p0.w + bb[3], 0.f);
        float h4 = fmaxf(acc[4] * s + p1.x + bb[4], 0.f);
        float h5 = fmaxf(acc[5] * s + p1.y + bb[5], 0.f);
        float h6 = fmaxf(acc[6] * s + p1.z + bb[6], 0.f);
        float h7 = fmaxf(acc[7] * s + p1.w + bb[7], 0.f);
        hout.x = pack_bf(h0, h1);
        hout.y = pack_bf(h2, h3);
        hout.z = pack_bf(h4, h5);
        hout.w = pack_bf(h6, h7);
    }
    *(uint4*)&hB[ln][c * 8] = hout;
    __syncthreads();

    const int lane = tid & 63;
    const int wid = tid >> 6;
    const int l15 = lane & 15;
    const int quad = lane >> 4;

    bf16x8 a = *(const bf16x8*)&hB[wid * 16 + l15][quad * 8];
    f32x4 accm[4];
#pragma unroll
    for (int j = 0; j < 4; ++j) {
        bf16x8 b = *(const bf16x8*)&wB[j * 16 + l15][quad * 8];
        accm[j] = __builtin_amdgcn_mfma_f32_16x16x32_bf16(
            a, b, (f32x4){0.f, 0.f, 0.f, 0.f}, 0, 0, 0);
    }

#pragma unroll
    for (int r = 0; r < 4; ++r) {
        int m = node0 + wid * 16 + quad * 4 + r;
        if (m >= nnodes) continue;
#pragma unroll
        for (int j = 0; j < 4; ++j) {
            float v = accm[j][r];
            if (j < 2) g_next[(size_t)m * 32 + j * 16 + l15] = f2bf_rne(v);
            else       p_next[(size_t)m * 32 + (j - 2) * 16 + l15] = v;
        }
    }
}

// fused gather + layer-5 finish + output projection
__global__ __launch_bounds__(256) void aggregate_final32(
        const unsigned short* __restrict__ gb_prev,
        const int* __restrict__ offs,
        const int* __restrict__ ssrc,
        const float* __restrict__ inv_deg,
        const float* __restrict__ p,
        const float* __restrict__ bias,
        const float* __restrict__ Wout,
        const float* __restrict__ bout,
        float* __restrict__ out, int nnodes) {
    int t = blockIdx.x * 256 + threadIdx.x;
    int node = t >> 2;
    int c = t & 3;
    if (node >= nnodes) return;
    int b = offs[node], e = offs[node + 1];
    const uint4* __restrict__ hb4 = (const uint4*)gb_prev;
    float acc[8] = {0.f, 0.f, 0.f, 0.f, 0.f, 0.f, 0.f, 0.f};
    int i = b;
    for (; i + 4 <= e; i += 4) {
        uint4 p0 = hb4[(size_t)ssrc[i] * 4 + c];
        uint4 p1 = hb4[(size_t)ssrc[i + 1] * 4 + c];
        uint4 p2 = hb4[(size_t)ssrc[i + 2] * 4 + c];
        uint4 p3 = hb4[(size_t)ssrc[i + 3] * 4 + c];
        acc8_bf(acc, p0);
        acc8_bf(acc, p1);
        acc8_bf(acc, p2);
        acc8_bf(acc, p3);
    }
    for (; i < e; ++i) acc8_bf(acc, hb4[(size_t)ssrc[i] * 4 + c]);
    float s = inv_deg[node];
    const float4* prow = (const float4*)(p + (size_t)node * 32 + c * 8);
    float4 p0 = prow[0], p1 = prow[1];
    const float* bb = bias + c * 8;
    const float* w = Wout + c * 8;
    float sum = 0.f;
    sum = fmaf(fmaxf(acc[0] * s + p0.x + bb[0], 0.f), w[0], sum);
    sum = fmaf(fmaxf(acc[1] * s + p0.y + bb[1], 0.f), w[1], sum);
    sum = fmaf(fmaxf(acc[2] * s + p0.z + bb[2], 0.f), w[2], sum);
    sum = fmaf(fmaxf(acc[3] * s + p0.w + bb[3], 0.f), w[3], sum);
    sum = fmaf(fmaxf(acc[4] * s + p1.x + bb[4], 0.f), w[4], sum);
    sum = fmaf(fmaxf(acc[5] * s + p1.y + bb[5], 0.f), w[5], sum);
    sum = fmaf(fmaxf(acc[6] * s + p1.z + bb[6], 0.f), w[6], sum);
    sum = fmaf(fmaxf(acc[7] * s + p1.w + bb[7], 0.f), w[7], sum);
    sum += __shfl_down(sum, 2, 4);
    sum += __shfl_down(sum, 1, 4);
    if (c == 0) out[node] = sum + bout[0];
}

// ---------------- launch ----------------

extern "C" void kernel_launch(void* const* d_in, const int* in_sizes, int n_in,
                              void* d_out, int out_size, void* d_ws, size_t ws_size,
                              hipStream_t stream) {
    const float* x      = (const float*)d_in[0];
    const int*   ei     = (const int*)d_in[1];
    const float* Wl1    = (const float*)d_in[3];
    const float* bl1    = (const float*)d_in[4];
    const float* Wr1    = (const float*)d_in[5];
    const float* Wl2    = (const float*)d_in[6];
    const float* bl2    = (const float*)d_in[7];
    const float* Wr2    = (const float*)d_in[8];
    const float* Wl3    = (const float*)d_in[9];
    const float* bl3    = (const float*)d_in[10];
    const float* Wr3    = (const float*)d_in[11];
    const float* Wl4    = (const float*)d_in[12];
    const float* bl4    = (const float*)d_in[13];
    const float* Wr4    = (const float*)d_in[14];
    const float* Wl5    = (const float*)d_in[15];
    const float* bl5    = (const float*)d_in[16];
    const float* Wr5    = (const float*)d_in[17];
    const float* W_out  = (const float*)d_in[18];
    const float* b_out  = (const float*)d_in[19];
    float* out = (float*)d_out;

    const int N = N_NODES, E = N_EDGES;
    const int* e_src = ei;
    const int* e_dst = ei + E;

    size_t off = 0;
    auto carve = [&](size_t bytes) {
        void* p = (char*)d_ws + off;
        off += (bytes + 255) & ~(size_t)255;
        return p;
    };
    int*   offsets  = (int*)carve((size_t)(N + 1) * 4);
    float* inv_deg  = (float*)carve((size_t)N * 4);
    int*   ssrc     = (int*)carve((size_t)E * 4);
    int*   blkCntT  = (int*)carve((size_t)NBUCK * NBUCK * 4);
    int*   blkBaseL = (int*)carve((size_t)NBUCK * NBUCK * 4);
    int*   bucketTotal = (int*)carve((size_t)NBUCK * 4);
    int*   bstart   = (int*)carve((size_t)(NBUCK + 1) * 4);
    int2*  staging  = (int2*)carve((size_t)E * 8);
    unsigned short* Wt  = (unsigned short*)carve((size_t)128 * 256 * 2);
    unsigned short* W3c = (unsigned short*)carve((size_t)64 * 128 * 2);
    unsigned short* W4c = (unsigned short*)carve((size_t)64 * 32 * 2);
    unsigned short* W5c = (unsigned short*)carve((size_t)64 * 32 * 2);
    float* agg      = (float*)carve((size_t)N * 128 * 4);
    float* bufA     = (float*)carve((size_t)N * 128 * 4);
    unsigned short* g3b = (unsigned short*)carve((size_t)N * 32 * 2);
    unsigned short* g4b = (unsigned short*)carve((size_t)N * 32 * 2);
    unsigned short* g5b = (unsigned short*)carve((size_t)N * 32 * 2);

    float* slotA = agg;                       // p3 / p5
    float* slotC = agg + (size_t)N * 64;      // p4
    unsigned short* h1_bf = (unsigned short*)bufA;
    unsigned short* aggB  = (unsigned short*)bufA + (size_t)N * 128;

    // --- CSR build: split 256-bucket counting sort (R17) ---
    pa_count<<<NBUCK, 256, 0, stream>>>(e_dst, blkCntT);
    pa_scan1<<<NBUCK, 256, 0, stream>>>(blkCntT, blkBaseL, bucketTotal);
    pa_scan2<<<1, 256, 0, stream>>>(bucketTotal, bstart, offsets);
    pa_scatter<<<NBUCK, 256, 0, stream>>>(e_src, e_dst, blkCntT, blkBaseL, bstart, staging);
    pc_fill<<<NBUCK, 512, 0, stream>>>(staging, bstart, ssrc, offsets, inv_deg);
    prep_all<<<176, 256, 0, stream>>>(Wl2, Wr2, Wl3, Wr3, Wl4, Wr4, Wl5, Wr5,
                                      Wt, W3c, W4c, W5c);

    const int gemm_grid = (N + 127) / 128;
    const int comb_grid = (N + 63) / 64;

    // --- layer 1: fused gather + linear (bf16 out) ---
    sage1_fused<<<(N * 4 + 255) / 256, 256, 0, stream>>>(x, offsets, ssrc, inv_deg,
                                                         Wl1, bl1, Wr1, h1_bf, N);

    // --- layer 2 + layer-3 products ---
    aggregate_bf128<<<(N * 16 + 255) / 256, 256, 0, stream>>>(h1_bf, offsets, ssrc,
                                                              inv_deg, aggB, N);
    gemm_l2_mfma<<<gemm_grid, 256, 0, stream>>>(aggB, h1_bf, Wt, bl2, W3c, g3b, slotA, N);

    // --- layer 3 finish + layer-4 products ---
    aggregate_combine32<<<comb_grid, 256, 0, stream>>>(g3b, offsets, ssrc, inv_deg,
                                                       slotA, bl3, W4c, g4b, slotC, N);

    // --- layer 4 finish + layer-5 products ---
    aggregate_combine32<<<comb_grid, 256, 0, stream>>>(g4b, offsets, ssrc, inv_deg,
                                                       slotC, bl4, W5c, g5b, slotA, N);

    // --- layer 5 finish + output projection ---
    aggregate_final32<<<(N * 4 + 255) / 256, 256, 0, stream>>>(g5b, offsets, ssrc, inv_deg,
                                                               slotA, bl5, W_out, b_out,
                                                               out, N);
}

// Round 20
// 323.880 us; speedup vs baseline: 1.8289x; 1.0750x over previous
//
#include <hip/hip_runtime.h>
#include <hip/hip_bf16.h>

#define N_NODES 100000
#define N_EDGES 1600000
#define NBUCK 256
#define NODES_PER_BUCKET 391        // 256*391 = 100096 >= 100000
#define EDGES_PER_CHUNK (N_EDGES / NBUCK)   // 6250 exactly
#define FILL_LDS_CAP 8192           // mean 6250, sigma~79 -> +24 sigma

typedef __bf16 bf16x8 __attribute__((ext_vector_type(8)));
typedef float f32x4 __attribute__((ext_vector_type(4)));

// ---------------- helpers ----------------

__device__ inline unsigned short f2bf_rne(float v) {
    unsigned u = __float_as_uint(v);
    u += 0x7fffu + ((u >> 16) & 1u);
    return (unsigned short)(u >> 16);
}

__device__ inline unsigned pack_bf(float a, float b) {
    return (unsigned)f2bf_rne(a) | ((unsigned)f2bf_rne(b) << 16);
}

__device__ inline void acc8_bf(float* a, uint4 p) {
    a[0] += __uint_as_float(p.x << 16);
    a[1] += __uint_as_float(p.x & 0xffff0000u);
    a[2] += __uint_as_float(p.y << 16);
    a[3] += __uint_as_float(p.y & 0xffff0000u);
    a[4] += __uint_as_float(p.z << 16);
    a[5] += __uint_as_float(p.z & 0xffff0000u);
    a[6] += __uint_as_float(p.w << 16);
    a[7] += __uint_as_float(p.w & 0xffff0000u);
}

// ---------------- CSR build: 256-bucket counting sort (split) --------------
// Staging entry packed: (src << 9) | local_dst  (src<2^17, local_dst<391<2^9)

__global__ __launch_bounds__(256) void pa_count(const int* __restrict__ dst,
                                                int* __restrict__ blkCntT) {
    __shared__ int hist[NBUCK];
    hist[threadIdx.x] = 0;
    __syncthreads();
    int b0 = blockIdx.x * EDGES_PER_CHUNK;
    int b1 = min(b0 + EDGES_PER_CHUNK, N_EDGES);
    for (int i = b0 + (int)threadIdx.x; i < b1; i += 256) {
        int d = __builtin_nontemporal_load(&dst[i]);
        atomicAdd(&hist[d / NODES_PER_BUCKET], 1);
    }
    __syncthreads();
    blkCntT[threadIdx.x * NBUCK + blockIdx.x] = hist[threadIdx.x];
}

__global__ __launch_bounds__(256) void pa_scan1(const int* __restrict__ blkCntT,
                                                int* __restrict__ blkBaseL,
                                                int* __restrict__ bucketTotal) {
    __shared__ int s[256];
    int t = threadIdx.x;
    int v = blkCntT[blockIdx.x * NBUCK + t];
    s[t] = v;
    __syncthreads();
    for (int off = 1; off < 256; off <<= 1) {
        int u = (t >= off) ? s[t - off] : 0;
        __syncthreads();
        s[t] += u;
        __syncthreads();
    }
    blkBaseL[blockIdx.x * NBUCK + t] = s[t] - v;
    if (t == 255) bucketTotal[blockIdx.x] = s[255];
}

__global__ __launch_bounds__(256) void pa_scan2(const int* __restrict__ bucketTotal,
                                                int* __restrict__ bstart,
                                                int* __restrict__ offsets) {
    __shared__ int s[256];
    int t = threadIdx.x;
    int v = bucketTotal[t];
    s[t] = v;
    __syncthreads();
    for (int off = 1; off < 256; off <<= 1) {
        int u = (t >= off) ? s[t - off] : 0;
        __syncthreads();
        s[t] += u;
        __syncthreads();
    }
    bstart[t] = s[t] - v;
    if (t == 255) {
        bstart[256] = s[255];
        offsets[N_NODES] = s[255];
    }
}

__global__ __launch_bounds__(256) void pa_scatter(const int* __restrict__ src,
                                                  const int* __restrict__ dst,
                                                  const int* __restrict__ blkCntT,
                                                  const int* __restrict__ blkBaseL,
                                                  const int* __restrict__ bstart,
                                                  int* __restrict__ staging) {
    __shared__ int runStart[NBUCK + 1];
    __shared__ int cur[NBUCK];
    __shared__ int gbase[NBUCK];
    __shared__ int buf[EDGES_PER_CHUNK];            // packed, 25 KB
    __shared__ unsigned char bucketOf[EDGES_PER_CHUNK];

    const int tid = threadIdx.x;
    const int g = blockIdx.x;
    const int b0 = g * EDGES_PER_CHUNK;
    const int b1 = min(b0 + EDGES_PER_CHUNK, N_EDGES);
    const int cnt = b1 - b0;

    {
        __shared__ int s[256];
        int v = blkCntT[tid * NBUCK + g];
        s[tid] = v;
        __syncthreads();
        for (int off = 1; off < 256; off <<= 1) {
            int u = (tid >= off) ? s[tid - off] : 0;
            __syncthreads();
            s[tid] += u;
            __syncthreads();
        }
        runStart[tid] = s[tid] - v;
        cur[tid] = s[tid] - v;
        gbase[tid] = bstart[tid] + blkBaseL[tid * NBUCK + g];
        if (tid == 255) runStart[256] = s[255];
    }
    __syncthreads();
    for (int i = b0 + tid; i < b1; i += 256) {
        int d = __builtin_nontemporal_load(&dst[i]);
        int s_ = __builtin_nontemporal_load(&src[i]);
        int k = d / NODES_PER_BUCKET;
        int ld = d - k * NODES_PER_BUCKET;
        int p = atomicAdd(&cur[k], 1);
        buf[p] = (s_ << 9) | ld;
    }
    __syncthreads();
    // bucket-of-index table (thread t fills bucket t's run)
    for (int i = runStart[tid]; i < runStart[tid + 1]; ++i)
        bucketOf[i] = (unsigned char)tid;
    __syncthreads();
    for (int i = tid; i < cnt; i += 256) {
        int k = bucketOf[i];
        staging[gbase[k] + (i - runStart[k])] = buf[i];
    }
}

// single global pass: bucket slice -> LDS, count/scan/scatter in LDS
__global__ __launch_bounds__(512) void pc_fill(const int* __restrict__ staging,
                                               const int* __restrict__ bstart,
                                               int* __restrict__ ssrc,
                                               int* __restrict__ offsets,
                                               float* __restrict__ inv_deg) {
    __shared__ int scnt[NODES_PER_BUCKET];
    __shared__ int sexc[NODES_PER_BUCKET];
    __shared__ int scur[NODES_PER_BUCKET];
    __shared__ int ebuf[FILL_LDS_CAP];    // 32 KB
    __shared__ int ssrcL[FILL_LDS_CAP];   // 32 KB

    const int tid = threadIdx.x;
    const int b = blockIdx.x;
    const int node0 = b * NODES_PER_BUCKET;
    const int nn = min(node0 + NODES_PER_BUCKET, N_NODES) - node0;
    if (nn <= 0) return;
    const int es = bstart[b], ee = bstart[b + 1];
    const int cnt = ee - es;
    const bool inLds = (cnt <= FILL_LDS_CAP);

    for (int j = tid; j < nn; j += 512) scnt[j] = 0;
    if (inLds)
        for (int i = tid; i < cnt; i += 512) ebuf[i] = staging[es + i];
    __syncthreads();

    if (inLds) {
        for (int i = tid; i < cnt; i += 512) atomicAdd(&scnt[ebuf[i] & 511], 1);
    } else {
        for (int i = es + tid; i < ee; i += 512)
            atomicAdd(&scnt[staging[i] & 511], 1);
    }
    __syncthreads();

    if (tid < 64) {
        int base = tid * 7;
        int vals[7];
        int run = 0;
#pragma unroll
        for (int j = 0; j < 7; ++j) {
            int idx = base + j;
            int c = (idx < nn) ? scnt[idx] : 0;
            vals[j] = run;
            run += c;
        }
        int inc = run;
#pragma unroll
        for (int off = 1; off < 64; off <<= 1) {
            int u = __shfl_up(inc, off, 64);
            if (tid >= off) inc += u;
        }
        int laneExcl = inc - run;
#pragma unroll
        for (int j = 0; j < 7; ++j) {
            int idx = base + j;
            if (idx < nn) sexc[idx] = laneExcl + vals[j];
        }
    }
    __syncthreads();

    for (int j = tid; j < nn; j += 512) {
        int c = scnt[j];
        int ex = sexc[j];
        offsets[node0 + j] = es + ex;
        inv_deg[node0 + j] = 1.0f / (float)max(c, 1);
        scur[j] = ex;
    }
    __syncthreads();

    if (inLds) {
        for (int i = tid; i < cnt; i += 512) {
            int e = ebuf[i];
            int p = atomicAdd(&scur[e & 511], 1);
            ssrcL[p] = e >> 9;
        }
        __syncthreads();
        for (int i = tid; i < cnt; i += 512) ssrc[es + i] = ssrcL[i];
    } else {
        for (int i = es + tid; i < ee; i += 512) {
            int e = staging[i];
            int p = atomicAdd(&scur[e & 511], 1);
            ssrc[es + p] = e >> 9;
        }
    }
}

// ---------------- layer 1 fused: gather + linear (2 -> 128, bf16 out) ------
// Weights staged in LDS (R19 post-mortem: per-thread global weight loads).

__global__ __launch_bounds__(256) void sage1_fused(const float* __restrict__ x,
                                                   const int* __restrict__ offs,
                                                   const int* __restrict__ ssrc,
                                                   const float* __restrict__ inv_deg,
                                                   const float* __restrict__ Wl,
                                                   const float* __restrict__ bl,
                                                   const float* __restrict__ Wr,
                                                   unsigned short* __restrict__ out_bf,
                                                   int nnodes) {
    __shared__ float wls[256], wrs[256], bls[128];
    int tid = threadIdx.x;
    if (tid < 256) {
        wls[tid] = Wl[tid];
        wrs[tid] = Wr[tid];
        if (tid < 128) bls[tid] = bl[tid];
    }
    __syncthreads();

    int t = blockIdx.x * 256 + tid;
    int node = t >> 2;
    int c = t & 3;
    if (node >= nnodes) return;
    const float2* __restrict__ x2 = (const float2*)x;
    int b = offs[node], e = offs[node + 1];
    float ax = 0.f, ay = 0.f;
    for (int i = b + c; i < e; i += 4) {
        float2 v = x2[ssrc[i]];
        ax += v.x;
        ay += v.y;
    }
    ax += __shfl_xor(ax, 1, 4);
    ay += __shfl_xor(ay, 1, 4);
    ax += __shfl_xor(ax, 2, 4);
    ay += __shfl_xor(ay, 2, 4);
    float s = inv_deg[node];
    ax *= s; ay *= s;
    float2 hh = x2[node];
    const float* wl0 = wls + c * 32;
    const float* wl1 = wls + 128 + c * 32;
    const float* wr0 = wrs + c * 32;
    const float* wr1 = wrs + 128 + c * 32;
    const float* bb = bls + c * 32;
    uint4* dst4 = (uint4*)(out_bf + (size_t)node * 128 + c * 32);
#pragma unroll
    for (int q = 0; q < 4; ++q) {
        unsigned vals[4];
#pragma unroll
        for (int pj = 0; pj < 4; ++pj) {
            int j = q * 8 + pj * 2;
            float v0 = fmaxf(bb[j] + ax * wl0[j] + ay * wl1[j] +
                             hh.x * wr0[j] + hh.y * wr1[j], 0.f);
            float v1 = fmaxf(bb[j + 1] + ax * wl0[j + 1] + ay * wl1[j + 1] +
                             hh.x * wr0[j + 1] + hh.y * wr1[j + 1], 0.f);
            vals[pj] = pack_bf(v0, v1);
        }
        dst4[q] = make_uint4(vals[0], vals[1], vals[2], vals[3]);
    }
}

// ---------------- aggregation (layer 2) ----------------

__global__ __launch_bounds__(256) void aggregate_bf128(const unsigned short* __restrict__ hb,
                                                       const int* __restrict__ offs,
                                                       const int* __restrict__ ssrc,
                                                       const float* __restrict__ inv_deg,
                                                       unsigned short* __restrict__ aggb,
                                                       int nnodes) {
    int t = blockIdx.x * 256 + threadIdx.x;
    if (t >= nnodes * 16) return;
    int node = t >> 4;
    int c = t & 15;
    int b = offs[node], e = offs[node + 1];
    const uint4* __restrict__ hb4 = (const uint4*)hb;
    float acc[8] = {0.f, 0.f, 0.f, 0.f, 0.f, 0.f, 0.f, 0.f};
    int i = b;
    for (; i + 4 <= e; i += 4) {
        uint4 p0 = hb4[(size_t)ssrc[i] * 16 + c];
        uint4 p1 = hb4[(size_t)ssrc[i + 1] * 16 + c];
        uint4 p2 = hb4[(size_t)ssrc[i + 2] * 16 + c];
        uint4 p3 = hb4[(size_t)ssrc[i + 3] * 16 + c];
        acc8_bf(acc, p0);
        acc8_bf(acc, p1);
        acc8_bf(acc, p2);
        acc8_bf(acc, p3);
    }
    for (; i < e; ++i) {
        uint4 p = hb4[(size_t)ssrc[i] * 16 + c];
        acc8_bf(acc, p);
    }
    float s = inv_deg[node];
    uint4 o;
    o.x = pack_bf(acc[0] * s, acc[1] * s);
    o.y = pack_bf(acc[2] * s, acc[3] * s);
    o.z = pack_bf(acc[4] * s, acc[5] * s);
    o.w = pack_bf(acc[6] * s, acc[7] * s);
    ((uint4*)aggb)[t] = o;
}

// ---------------- weight prep (single dispatch) ----------------

__global__ __launch_bounds__(256) void prep_all(const float* __restrict__ Wl2,
                                                const float* __restrict__ Wr2,
                                                const float* __restrict__ Wl3,
                                                const float* __restrict__ Wr3,
                                                const float* __restrict__ Wl4,
                                                const float* __restrict__ Wr4,
                                                const float* __restrict__ Wl5,
                                                const float* __restrict__ Wr5,
                                                unsigned short* __restrict__ Wt,
                                                unsigned short* __restrict__ W3c,
                                                unsigned short* __restrict__ W4c,
                                                unsigned short* __restrict__ W5c) {
    int idx = blockIdx.x * 256 + threadIdx.x;
    if (idx < 32768) {
        int n = idx >> 8, k = idx & 255;
        float v = (k < 128) ? Wl2[k * 128 + n] : Wr2[(k - 128) * 128 + n];
        Wt[idx] = f2bf_rne(v);
    } else if (idx < 32768 + 8192) {
        int j = idx - 32768;
        int n = j >> 7, k = j & 127;
        float v = (n < 32) ? Wl3[k * 32 + n] : Wr3[k * 32 + (n - 32)];
        W3c[j] = f2bf_rne(v);
    } else if (idx < 32768 + 8192 + 2048) {
        int j = idx - 32768 - 8192;
        int n = j >> 5, k = j & 31;
        float v = (n < 32) ? Wl4[k * 32 + n] : Wr4[k * 32 + (n - 32)];
        W4c[j] = f2bf_rne(v);
    } else if (idx < 32768 + 8192 + 4096) {
        int j = idx - 32768 - 8192 - 2048;
        int n = j >> 5, k = j & 31;
        float v = (n < 32) ? Wl5[k * 32 + n] : Wr5[k * 32 + (n - 32)];
        W5c[j] = f2bf_rne(v);
    }
}

// ---------------- layer-2 MFMA GEMM + fused layer-3 products ----------------

__global__ __launch_bounds__(256) void gemm_l2_mfma(const unsigned short* __restrict__ Ab,
                                                    const unsigned short* __restrict__ Hb,
                                                    const unsigned short* __restrict__ Wt,
                                                    const float* __restrict__ bias,
                                                    const unsigned short* __restrict__ W3c,
                                                    unsigned short* __restrict__ g3b,
                                                    float* __restrict__ p3, int M) {
    constexpr int BM = 128, BK = 64;
    __shared__ unsigned short smem[26112];
#define SA(r, c) smem[(r) * 72 + (c)]
#define SB(r, c) smem[9216 + (r) * 72 + (c)]
#define SH(r, c) smem[(r) * 136 + (c)]
#define SW3(r, c) smem[17408 + (r) * 136 + (c)]

    const int tid = threadIdx.x;
    const int m0 = blockIdx.x * BM;
    const int lane = tid & 63;
    const int wid = tid >> 6;
    const int l15 = lane & 15;
    const int quad = lane >> 4;
    const int wm = (wid >> 1) * 64;
    const int wn = (wid & 1) * 64;

    f32x4 acc[4][4];
#pragma unroll
    for (int i = 0; i < 4; ++i)
#pragma unroll
        for (int j = 0; j < 4; ++j) acc[i][j] = (f32x4){0.f, 0.f, 0.f, 0.f};

    for (int k0 = 0; k0 < 256; k0 += BK) {
        const uint4* __restrict__ srcA = (const uint4*)((k0 < 128) ? Ab : Hb);
        const int kc = (k0 & 64) >> 3;
#pragma unroll
        for (int l = 0; l < 4; ++l) {
            int idx = tid + l * 256;
            int row = idx >> 3;
            int c8 = idx & 7;
            int gr = min(m0 + row, M - 1);
            uint4 va = srcA[(size_t)gr * 16 + kc + c8];
            *(uint4*)&SA(row, c8 * 8) = va;
            uint4 vb = ((const uint4*)Wt)[(size_t)row * 32 + (k0 >> 3) + c8];
            *(uint4*)&SB(row, c8 * 8) = vb;
        }
        __syncthreads();

#pragma unroll
        for (int ks = 0; ks < BK; ks += 32) {
            bf16x8 a[4], b[4];
#pragma unroll
            for (int t = 0; t < 4; ++t) {
                a[t] = *(const bf16x8*)&SA(wm + t * 16 + l15, ks + quad * 8);
                b[t] = *(const bf16x8*)&SB(wn + t * 16 + l15, ks + quad * 8);
            }
#pragma unroll
            for (int i = 0; i < 4; ++i)
#pragma unroll
                for (int j = 0; j < 4; ++j)
                    acc[i][j] = __builtin_amdgcn_mfma_f32_16x16x32_bf16(
                        a[i], b[j], acc[i][j], 0, 0, 0);
        }
        __syncthreads();
    }

#pragma unroll
    for (int j = 0; j < 4; ++j) {
        int n = wn + j * 16 + l15;
        float bv = bias[n];
#pragma unroll
        for (int i = 0; i < 4; ++i) {
#pragma unroll
            for (int r = 0; r < 4; ++r) {
                int ml = wm + i * 16 + quad * 4 + r;
                SH(ml, n) = f2bf_rne(fmaxf(acc[i][j][r] + bv, 0.f));
            }
        }
    }
#pragma unroll
    for (int l = 0; l < 4; ++l) {
        int idx = tid + l * 256;
        int row = idx >> 4;
        int c8 = idx & 15;
        uint4 v = ((const uint4*)W3c)[(size_t)row * 16 + c8];
        *(uint4*)&SW3(row, c8 * 8) = v;
    }
    __syncthreads();

    f32x4 acc2[2][4];
#pragma unroll
    for (int i = 0; i < 2; ++i)
#pragma unroll
        for (int j = 0; j < 4; ++j) acc2[i][j] = (f32x4){0.f, 0.f, 0.f, 0.f};

#pragma unroll
    for (int ks = 0; ks < 128; ks += 32) {
        bf16x8 a[2], b[4];
#pragma unroll
        for (int i = 0; i < 2; ++i)
            a[i] = *(const bf16x8*)&SH(wid * 32 + i * 16 + l15, ks + quad * 8);
#pragma unroll
        for (int j = 0; j < 4; ++j)
            b[j] = *(const bf16x8*)&SW3(j * 16 + l15, ks + quad * 8);
#pragma unroll
        for (int i = 0; i < 2; ++i)
#pragma unroll
            for (int j = 0; j < 4; ++j)
                acc2[i][j] = __builtin_amdgcn_mfma_f32_16x16x32_bf16(
                    a[i], b[j], acc2[i][j], 0, 0, 0);
    }

#pragma unroll
    for (int i = 0; i < 2; ++i) {
#pragma unroll
        for (int r = 0; r < 4; ++r) {
            int m = m0 + wid * 32 + i * 16 + quad * 4 + r;
            if (m >= M) continue;
#pragma unroll
            for (int j = 0; j < 4; ++j) {
                float v = acc2[i][j][r];
                if (j < 2) g3b[(size_t)m * 32 + j * 16 + l15] = f2bf_rne(v);
                else       p3[(size_t)m * 32 + (j - 2) * 16 + l15] = v;
            }
        }
    }
#undef SA
#undef SB
#undef SH
#undef SW3
}

// ---------------- fused gather + combine + next-layer products --------------

__global__ __launch_bounds__(256) void aggregate_combine32(
        const unsigned short* __restrict__ gb_prev,
        const int* __restrict__ offs,
        const int* __restrict__ ssrc,
        const float* __restrict__ inv_deg,
        const float* __restrict__ p,
        const float* __restrict__ bias,
        const unsigned short* __restrict__ Wc,
        unsigned short* __restrict__ g_next,
        float* __restrict__ p_next, int nnodes) {
    __shared__ unsigned short hB[64][40];
    __shared__ unsigned short wB[64][40];

    const int tid = threadIdx.x;
    const int node0 = blockIdx.x * 64;
    const int node = node0 + (tid >> 2);
    const int c = tid & 3;
    const int ln = tid >> 2;

#pragma unroll
    for (int l = 0; l < 2; ++l) {
        int id = tid + l * 256;
        int r = id >> 3, cc = id & 7;
        uint2 v = ((const uint2*)Wc)[(size_t)r * 8 + cc];
        *(uint2*)&wB[r][cc * 4] = v;
    }

    uint4 hout = make_uint4(0u, 0u, 0u, 0u);
    if (node < nnodes) {
        int b = offs[node], e = offs[node + 1];
        const uint4* __restrict__ hb4 = (const uint4*)gb_prev;
        float acc[8] = {0.f, 0.f, 0.f, 0.f, 0.f, 0.f, 0.f, 0.f};
        int i = b;
        for (; i + 4 <= e; i += 4) {
            uint4 p0 = hb4[(size_t)ssrc[i] * 4 + c];
            uint4 p1 = hb4[(size_t)ssrc[i + 1] * 4 + c];
            uint4 p2 = hb4[(size_t)ssrc[i + 2] * 4 + c];
            uint4 p3 = hb4[(size_t)ssrc[i + 3] * 4 + c];
            acc8_bf(acc, p0);
            acc8_bf(acc, p1);
            acc8_bf(acc, p2);
            acc8_bf(acc, p3);
        }
        for (; i < e; ++i) acc8_bf(acc, hb4[(size_t)ssrc[i] * 4 + c]);
        float s = inv_deg[node];
        const float4* prow = (const float4*)(p + (size_t)node * 32 + c * 8);
        float4 p0 = prow[0], p1 = prow[1];
        const float* bb = bias + c * 8;
        float h0 = fmaxf(acc[0] * s + p0.x + bb[0], 0.f);
        float h1 = fmaxf(acc[1] * s + p0.y + bb[1], 0.f);
        float h2 = fmaxf(acc[2] * s + p0.z + bb[2], 0.f);
        float h3 = fmaxf(acc[3] * s + p0.w + bb[3], 0.f);
        float h4 = fmaxf(acc[4] * s + p1.x + bb[4], 0.f);
        float h5 = fmaxf(acc[5] * s + p1.y + bb[5], 0.f);
        float h6 = fmaxf(acc[6] * s + p1.z + bb[6], 0.f);
        float h7 = fmaxf(acc[7] * s + p1.w + bb[7], 0.f);
        hout.x = pack_bf(h0, h1);
        hout.y = pack_bf(h2, h3);
        hout.z = pack_bf(h4, h5);
        hout.w = pack_bf(h6, h7);
    }
    *(uint4*)&hB[ln][c * 8] = hout;
    __syncthreads();

    const int lane = tid & 63;
    const int wid = tid >> 6;
    const int l15 = lane & 15;
    const int quad = lane >> 4;

    bf16x8 a = *(const bf16x8*)&hB[wid * 16 + l15][quad * 8];
    f32x4 accm[4];
#pragma unroll
    for (int j = 0; j < 4; ++j) {
        bf16x8 b = *(const bf16x8*)&wB[j * 16 + l15][quad * 8];
        accm[j] = __builtin_amdgcn_mfma_f32_16x16x32_bf16(
            a, b, (f32x4){0.f, 0.f, 0.f, 0.f}, 0, 0, 0);
    }

#pragma unroll
    for (int r = 0; r < 4; ++r) {
        int m = node0 + wid * 16 + quad * 4 + r;
        if (m >= nnodes) continue;
#pragma unroll
        for (int j = 0; j < 4; ++j) {
            float v = accm[j][r];
            if (j < 2) g_next[(size_t)m * 32 + j * 16 + l15] = f2bf_rne(v);
            else       p_next[(size_t)m * 32 + (j - 2) * 16 + l15] = v;
        }
    }
}

// fused gather + layer-5 finish + output projection
__global__ __launch_bounds__(256) void aggregate_final32(
        const unsigned short* __restrict__ gb_prev,
        const int* __restrict__ offs,
        const int* __restrict__ ssrc,
        const float* __restrict__ inv_deg,
        const float* __restrict__ p,
        const float* __restrict__ bias,
        const float* __restrict__ Wout,
        const float* __restrict__ bout,
        float* __restrict__ out, int nnodes) {
    int t = blockIdx.x * 256 + threadIdx.x;
    int node = t >> 2;
    int c = t & 3;
    if (node >= nnodes) return;
    int b = offs[node], e = offs[node + 1];
    const uint4* __restrict__ hb4 = (const uint4*)gb_prev;
    float acc[8] = {0.f, 0.f, 0.f, 0.f, 0.f, 0.f, 0.f, 0.f};
    int i = b;
    for (; i + 4 <= e; i += 4) {
        uint4 p0 = hb4[(size_t)ssrc[i] * 4 + c];
        uint4 p1 = hb4[(size_t)ssrc[i + 1] * 4 + c];
        uint4 p2 = hb4[(size_t)ssrc[i + 2] * 4 + c];
        uint4 p3 = hb4[(size_t)ssrc[i + 3] * 4 + c];
        acc8_bf(acc, p0);
        acc8_bf(acc, p1);
        acc8_bf(acc, p2);
        acc8_bf(acc, p3);
    }
    for (; i < e; ++i) acc8_bf(acc, hb4[(size_t)ssrc[i] * 4 + c]);
    float s = inv_deg[node];
    const float4* prow = (const float4*)(p + (size_t)node * 32 + c * 8);
    float4 p0 = prow[0], p1 = prow[1];
    const float* bb = bias + c * 8;
    const float* w = Wout + c * 8;
    float sum = 0.f;
    sum = fmaf(fmaxf(acc[0] * s + p0.x + bb[0], 0.f), w[0], sum);
    sum = fmaf(fmaxf(acc[1] * s + p0.y + bb[1], 0.f), w[1], sum);
    sum = fmaf(fmaxf(acc[2] * s + p0.z + bb[2], 0.f), w[2], sum);
    sum = fmaf(fmaxf(acc[3] * s + p0.w + bb[3], 0.f), w[3], sum);
    sum = fmaf(fmaxf(acc[4] * s + p1.x + bb[4], 0.f), w[4], sum);
    sum = fmaf(fmaxf(acc[5] * s + p1.y + bb[5], 0.f), w[5], sum);
    sum = fmaf(fmaxf(acc[6] * s + p1.z + bb[6], 0.f), w[6], sum);
    sum = fmaf(fmaxf(acc[7] * s + p1.w + bb[7], 0.f), w[7], sum);
    sum += __shfl_down(sum, 2, 4);
    sum += __shfl_down(sum, 1, 4);
    if (c == 0) out[node] = sum + bout[0];
}

// ---------------- launch ----------------

extern "C" void kernel_launch(void* const* d_in, const int* in_sizes, int n_in,
                              void* d_out, int out_size, void* d_ws, size_t ws_size,
                              hipStream_t stream) {
    const float* x      = (const float*)d_in[0];
    const int*   ei     = (const int*)d_in[1];
    const float* Wl1    = (const float*)d_in[3];
    const float* bl1    = (const float*)d_in[4];
    const float* Wr1    = (const float*)d_in[5];
    const float* Wl2    = (const float*)d_in[6];
    const float* bl2    = (const float*)d_in[7];
    const float* Wr2    = (const float*)d_in[8];
    const float* Wl3    = (const float*)d_in[9];
    const float* bl3    = (const float*)d_in[10];
    const float* Wr3    = (const float*)d_in[11];
    const float* Wl4    = (const float*)d_in[12];
    const float* bl4    = (const float*)d_in[13];
    const float* Wr4    = (const float*)d_in[14];
    const float* Wl5    = (const float*)d_in[15];
    const float* bl5    = (const float*)d_in[16];
    const float* Wr5    = (const float*)d_in[17];
    const float* W_out  = (const float*)d_in[18];
    const float* b_out  = (const float*)d_in[19];
    float* out = (float*)d_out;

    const int N = N_NODES, E = N_EDGES;
    const int* e_src = ei;
    const int* e_dst = ei + E;

    size_t off = 0;
    auto carve = [&](size_t bytes) {
        void* p = (char*)d_ws + off;
        off += (bytes + 255) & ~(size_t)255;
        return p;
    };
    int*   offsets  = (int*)carve((size_t)(N + 1) * 4);
    float* inv_deg  = (float*)carve((size_t)N * 4);
    int*   ssrc     = (int*)carve((size_t)E * 4);
    int*   blkCntT  = (int*)carve((size_t)NBUCK * NBUCK * 4);
    int*   blkBaseL = (int*)carve((size_t)NBUCK * NBUCK * 4);
    int*   bucketTotal = (int*)carve((size_t)NBUCK * 4);
    int*   bstart   = (int*)carve((size_t)(NBUCK + 1) * 4);
    int*   staging  = (int*)carve((size_t)E * 4);
    unsigned short* Wt  = (unsigned short*)carve((size_t)128 * 256 * 2);
    unsigned short* W3c = (unsigned short*)carve((size_t)64 * 128 * 2);
    unsigned short* W4c = (unsigned short*)carve((size_t)64 * 32 * 2);
    unsigned short* W5c = (unsigned short*)carve((size_t)64 * 32 * 2);
    float* agg      = (float*)carve((size_t)N * 128 * 4);
    float* bufA     = (float*)carve((size_t)N * 128 * 4);
    unsigned short* g3b = (unsigned short*)carve((size_t)N * 32 * 2);
    unsigned short* g4b = (unsigned short*)carve((size_t)N * 32 * 2);
    unsigned short* g5b = (unsigned short*)carve((size_t)N * 32 * 2);

    float* slotA = agg;                       // p3 / p5
    float* slotC = agg + (size_t)N * 64;      // p4
    unsigned short* h1_bf = (unsigned short*)bufA;
    unsigned short* aggB  = (unsigned short*)bufA + (size_t)N * 128;

    // --- CSR build: split 256-bucket counting sort (packed staging) ---
    pa_count<<<NBUCK, 256, 0, stream>>>(e_dst, blkCntT);
    pa_scan1<<<NBUCK, 256, 0, stream>>>(blkCntT, blkBaseL, bucketTotal);
    pa_scan2<<<1, 256, 0, stream>>>(bucketTotal, bstart, offsets);
    pa_scatter<<<NBUCK, 256, 0, stream>>>(e_src, e_dst, blkCntT, blkBaseL, bstart, staging);
    pc_fill<<<NBUCK, 512, 0, stream>>>(staging, bstart, ssrc, offsets, inv_deg);
    prep_all<<<176, 256, 0, stream>>>(Wl2, Wr2, Wl3, Wr3, Wl4, Wr4, Wl5, Wr5,
                                      Wt, W3c, W4c, W5c);

    const int gemm_grid = (N + 127) / 128;
    const int comb_grid = (N + 63) / 64;

    // --- layer 1: fused gather + linear (bf16 out) ---
    sage1_fused<<<(N * 4 + 255) / 256, 256, 0, stream>>>(x, offsets, ssrc, inv_deg,
                                                         Wl1, bl1, Wr1, h1_bf, N);

    // --- layer 2 + layer-3 products ---
    aggregate_bf128<<<(N * 16 + 255) / 256, 256, 0, stream>>>(h1_bf, offsets, ssrc,
                                                              inv_deg, aggB, N);
    gemm_l2_mfma<<<gemm_grid, 256, 0, stream>>>(aggB, h1_bf, Wt, bl2, W3c, g3b, slotA, N);

    // --- layer 3 finish + layer-4 products ---
    aggregate_combine32<<<comb_grid, 256, 0, stream>>>(g3b, offsets, ssrc, inv_deg,
                                                       slotA, bl3, W4c, g4b, slotC, N);

    // --- layer 4 finish + layer-5 products ---
    aggregate_combine32<<<comb_grid, 256, 0, stream>>>(g4b, offsets, ssrc, inv_deg,
                                                       slotC, bl4, W5c, g5b, slotA, N);

    // --- layer 5 finish + output projection ---
    aggregate_final32<<<(N * 4 + 255) / 256, 256, 0, stream>>>(g5b, offsets, ssrc, inv_deg,
                                                               slotA, bl5, W_out, b_out,
                                                               out, N);
}